// Round 3
// baseline (129.514 us; speedup 1.0000x reference)
//
#include <hip/hip_runtime.h>
#include <hip/hip_bf16.h>

#define EPSV 1e-5f
#define PITCH 36              // shorts per pcol row (32 ci + 4 pad) = 72 B = 18 dwords
#define PCOLS 516

typedef short bf16x8 __attribute__((ext_vector_type(8)));
typedef short bf16x4 __attribute__((ext_vector_type(4)));
typedef float f32x4  __attribute__((ext_vector_type(4)));

__device__ __forceinline__ short f2bf(float f){
  unsigned u = __float_as_uint(f);
  u += 0x7fff + ((u >> 16) & 1);     // RNE
  return (short)(u >> 16);
}
__device__ __forceinline__ int pk2(float a, float b){
  __hip_bfloat162 h = __float22bfloat162_rn(float2{a, b});
  return *reinterpret_cast<int*>(&h);
}

// ---------------------------------------------------------------------------
// Kernel A: Wb[b][j][co][ci] = bf16(conv_w[co][ci][j] + scale * (B@A)[b][co][ci*5+j])
// ---------------------------------------------------------------------------
__global__ void build_weights(const float* __restrict__ A_flat,
                              const float* __restrict__ B_flat,
                              const float* __restrict__ conv_w,
                              const float* __restrict__ scale_p,
                              short* __restrict__ Wb){
  int idx = blockIdx.x * 256 + threadIdx.x;   // ((b*5+j)*128 + co)*64 + ci
  int ci = idx & 63;
  int co = (idx >> 6) & 127;
  int bj = idx >> 13;          // 0..159
  int b  = bj / 5;
  int j  = bj - 5 * b;
  int m  = ci * 5 + j;
  const float* Bp = B_flat + (b * 128 + co) * 8;
  const float* Ap = A_flat + b * 8 * 320 + m;
  float d = 0.f;
#pragma unroll
  for (int r = 0; r < 8; ++r) d = fmaf(Bp[r], Ap[r * 320], d);
  float w = conv_w[co * 320 + m] + scale_p[0] * d;
  Wb[idx] = f2bf(w);
}

// ---------------------------------------------------------------------------
// Kernel B: block = (sample, group), 512 thr / 8 waves, 2 blocks/CU.
// 4 phases = 2 t-halves x 2 ci-chunks. Parity-split LDS (even/odd x-cols):
// stride-2 conv taps touch one parity each -> lane->pcol stride 1 ->
// conflict-light staging writes and fragment reads.
// ---------------------------------------------------------------------------
__global__ __launch_bounds__(512, 4)
void conv_gn_mfma(const float* __restrict__ x,
                  const short* __restrict__ Wb,
                  const float* __restrict__ conv_b,
                  const float* __restrict__ gamma,
                  const float* __restrict__ beta,
                  float* __restrict__ out){
  __shared__ short xe[PCOLS * PITCH];   // even x-cols: [pcol][ci32 + pad]
  __shared__ short xo[PCOLS * PITCH];   // odd  x-cols
  __shared__ float redS[8], redQ[8], bc2[2];

  const int bid    = blockIdx.x;
  const int sample = bid & 255;         // bid%8 == sample%8 -> 4 groups same XCD
  const int g      = bid >> 8;
  const int b      = sample >> 3;
  const int tid    = threadIdx.x;
  const int lane   = tid & 63;
  const int wid    = tid >> 6;          // 0..7
  const int l16    = lane & 15;
  const int lk     = lane >> 4;         // 0..3

  f32x4 acc[2][8];
#pragma unroll
  for (int m2 = 0; m2 < 2; ++m2)
#pragma unroll
    for (int n = 0; n < 8; ++n) acc[m2][n] = (f32x4){0.f,0.f,0.f,0.f};

  const size_t wb_base = (size_t)b * 5 * 128 * 64;
  const float* xsamp = x + (size_t)sample * 64 * 2048;

#pragma unroll
  for (int ph = 0; ph < 4; ++ph) {
    const int th = ph >> 1;             // t-half: out t in [th*512, th*512+512)
    const int ch = ph & 1;              // ci chunk: [ch*32, ch*32+32)

    if (ph) __syncthreads();            // previous compute done before overwrite
    // ---- stage: x[ci ch*32..+32][th*1024-2 .. th*1024+1025] -> xe/xo (bf16)
    {
      const float* xbase = xsamp + (size_t)(ch * 32) * 2048;
      const float* xr = xbase + (size_t)(wid * 4) * 2048 + th * 1024;
#pragma unroll 2
      for (int pass = 0; pass < 8; ++pass) {
        int c0 = pass * 128 + lane * 2;             // local x-col (8B aligned)
        float2 v0 = *(const float2*)(xr + 0 * 2048 + c0);
        float2 v1 = *(const float2*)(xr + 1 * 2048 + c0);
        float2 v2 = *(const float2*)(xr + 2 * 2048 + c0);
        float2 v3 = *(const float2*)(xr + 3 * 2048 + c0);
        int pcol = pass * 64 + lane + 1;            // lane->pcol stride 1
        int2 ev = { pk2(v0.x, v1.x), pk2(v2.x, v3.x) };
        int2 od = { pk2(v0.y, v1.y), pk2(v2.y, v3.y) };
        *(int2*)(xe + pcol * PITCH + wid * 4) = ev;
        *(int2*)(xo + pcol * PITCH + wid * 4) = od;
      }
      // halo cols: pcol 0 (x-cols th*1024-2/-1) and pcol 513 (+1024/+1025)
      if (tid < 128) {
        int which = tid >> 5;           // 0:L-even 1:L-odd 2:R-even 3:R-odd
        int ci    = tid & 31;
        int xc    = th * 1024 + ((which < 2) ? (which - 2) : (1024 + (which & 1)));
        float v = (xc >= 0 && xc < 2048) ? xbase[(size_t)ci * 2048 + xc] : 0.f;
        short* arr = (which & 1) ? xo : xe;
        arr[((which < 2) ? 0 : 513) * PITCH + ci] = f2bf(v);
      }
    }
    __syncthreads();
    // ---- compute: 5 taps x 4 n-frags x 2 m-frags, K=32 (this ci chunk)
#pragma unroll
    for (int j = 0; j < 5; ++j) {
      const short* apb = Wb + wb_base + (size_t)(j * 128 + g * 32) * 64 + ch * 32 + lk * 8;
      bf16x8 a0 = *(const bf16x8*)(apb + (size_t)l16 * 64);
      bf16x8 a1 = *(const bf16x8*)(apb + (size_t)(l16 + 16) * 64);
      const short* arr = (j & 1) ? xo : xe;
      const int joff = (j & 1) ? ((j - 1) >> 1) : (j >> 1);
#pragma unroll
      for (int nn = 0; nn < 4; ++nn) {
        int tloc = wid * 64 + nn * 16 + l16;        // t within this half
        const short* bp = arr + (tloc + joff) * PITCH + lk * 8;
        bf16x4 lo = *(const bf16x4*)bp;
        bf16x4 hi = *(const bf16x4*)(bp + 4);
        bf16x8 bfr = {lo[0],lo[1],lo[2],lo[3],hi[0],hi[1],hi[2],hi[3]};
        const int n = th * 4 + nn;                  // static (ph unrolled)
        acc[0][n] = __builtin_amdgcn_mfma_f32_16x16x32_bf16(a0, bfr, acc[0][n], 0, 0, 0);
        acc[1][n] = __builtin_amdgcn_mfma_f32_16x16x32_bf16(a1, bfr, acc[1][n], 0, 0, 0);
      }
    }
  }

  // ---- epilogue: bias + ReLU + GroupNorm over 32co x 1024t
  float cb_[2][4], ga_[2][4], be_[2][4];
#pragma unroll
  for (int m2 = 0; m2 < 2; ++m2)
#pragma unroll
    for (int r = 0; r < 4; ++r) {
      int co = g * 32 + m2 * 16 + lk * 4 + r;
      cb_[m2][r] = conv_b[co];
      ga_[m2][r] = gamma[co];
      be_[m2][r] = beta[co];
    }
  float s1 = 0.f, s2 = 0.f;
#pragma unroll
  for (int m2 = 0; m2 < 2; ++m2)
#pragma unroll
    for (int n = 0; n < 8; ++n)
#pragma unroll
      for (int r = 0; r < 4; ++r) {
        float v = acc[m2][n][r] + cb_[m2][r];
        v = v > 0.f ? v : 0.f;
        acc[m2][n][r] = v;
        s1 += v;
        s2 = fmaf(v, v, s2);
      }
#pragma unroll
  for (int off = 32; off; off >>= 1) {
    s1 += __shfl_down(s1, off);
    s2 += __shfl_down(s2, off);
  }
  if (lane == 0) { redS[wid] = s1; redQ[wid] = s2; }
  __syncthreads();
  if (tid == 0) {
    float a = 0.f, q = 0.f;
#pragma unroll
    for (int w = 0; w < 8; ++w) { a += redS[w]; q += redQ[w]; }
    float mean = a * (1.f / 32768.f);
    float var  = q * (1.f / 32768.f) - mean * mean;
    bc2[0] = mean;
    bc2[1] = rsqrtf(var + EPSV);
  }
  __syncthreads();
  const float mean = bc2[0], inv = bc2[1];
  float* ob = out + (size_t)sample * 128 * 1024;
#pragma unroll
  for (int m2 = 0; m2 < 2; ++m2)
#pragma unroll
    for (int r = 0; r < 4; ++r) {
      int co = g * 32 + m2 * 16 + lk * 4 + r;
      float aa = ga_[m2][r] * inv;
      float bb = be_[m2][r] - mean * aa;
      float* orow = ob + (size_t)co * 1024 + l16;
#pragma unroll
      for (int n = 0; n < 8; ++n) {
        int t = (n >> 2) * 512 + wid * 64 + (n & 3) * 16;
        orow[t] = acc[m2][n][r] * aa + bb;
      }
    }
}

// ---------------------------------------------------------------------------
extern "C" void kernel_launch(void* const* d_in, const int* in_sizes, int n_in,
                              void* d_out, int out_size, void* d_ws, size_t ws_size,
                              hipStream_t stream) {
  const float* x       = (const float*)d_in[0];
  const float* A_flat  = (const float*)d_in[1];
  const float* B_flat  = (const float*)d_in[2];
  const float* conv_w  = (const float*)d_in[3];
  const float* conv_b  = (const float*)d_in[4];
  const float* gamma   = (const float*)d_in[5];
  const float* beta    = (const float*)d_in[6];
  const float* scale_p = (const float*)d_in[9];

  float* out = (float*)d_out;
  short* Wb  = (short*)d_ws;   // 32*5*128*64 bf16 = 2.62 MB

  build_weights<<<5120, 256, 0, stream>>>(A_flat, B_flat, conv_w, scale_p, Wb);
  conv_gn_mfma<<<1024, 512, 0, stream>>>(x, Wb, conv_b, gamma, beta, out);
}

// Round 4
// 106.440 us; speedup vs baseline: 1.2168x; 1.2168x over previous
//
#include <hip/hip_runtime.h>
#include <hip/hip_bf16.h>

#define EPSV 1e-5f
#define PITCH 36              // shorts per pcol row (32 ci + 4 pad) = 72 B = 18 dwords
#define PCOLS 516

typedef short bf16x8 __attribute__((ext_vector_type(8)));
typedef short bf16x4 __attribute__((ext_vector_type(4)));
typedef float f32x4  __attribute__((ext_vector_type(4)));

__device__ __forceinline__ short f2bf(float f){
  unsigned u = __float_as_uint(f);
  u += 0x7fff + ((u >> 16) & 1);     // RNE
  return (short)(u >> 16);
}
__device__ __forceinline__ int pk2(float a, float b){
  __hip_bfloat162 h = __float22bfloat162_rn(float2{a, b});
  return *reinterpret_cast<int*>(&h);
}

// ---------------------------------------------------------------------------
// Kernel A: Wb[b][j][co][ci] = bf16(conv_w[co][ci][j] + scale * (B@A)[b][co][ci*5+j])
// ---------------------------------------------------------------------------
__global__ void build_weights(const float* __restrict__ A_flat,
                              const float* __restrict__ B_flat,
                              const float* __restrict__ conv_w,
                              const float* __restrict__ scale_p,
                              short* __restrict__ Wb){
  int idx = blockIdx.x * 256 + threadIdx.x;   // ((b*5+j)*128 + co)*64 + ci
  int ci = idx & 63;
  int co = (idx >> 6) & 127;
  int bj = idx >> 13;          // 0..159
  int b  = bj / 5;
  int j  = bj - 5 * b;
  int m  = ci * 5 + j;
  const float* Bp = B_flat + (b * 128 + co) * 8;
  const float* Ap = A_flat + b * 8 * 320 + m;
  float d = 0.f;
#pragma unroll
  for (int r = 0; r < 8; ++r) d = fmaf(Bp[r], Ap[r * 320], d);
  float w = conv_w[co * 320 + m] + scale_p[0] * d;
  Wb[idx] = f2bf(w);
}

// ---------------------------------------------------------------------------
// Kernel B: block = (sample, group), 512 thr / 8 waves, 2 blocks/CU.
// 4 phases = 2 t-halves x 2 ci-chunks. Parity-split LDS (even/odd x-cols).
// Swizzle: 4 group-blocks of one sample are 8 bids apart -> same XCD,
// co-resident -> x read once through L2 (R2-verified: 67 MB fetch).
// ---------------------------------------------------------------------------
__global__ __launch_bounds__(512, 4)
void conv_gn_mfma(const float* __restrict__ x,
                  const short* __restrict__ Wb,
                  const float* __restrict__ conv_b,
                  const float* __restrict__ gamma,
                  const float* __restrict__ beta,
                  float* __restrict__ out){
  __shared__ short xe[PCOLS * PITCH];   // even x-cols: [pcol][ci32 + pad]
  __shared__ short xo[PCOLS * PITCH];   // odd  x-cols
  __shared__ float redS[8], redQ[8], bc2[2];

  const int bid    = blockIdx.x;
  const int sample = ((bid & 7) << 5) + (bid >> 5);  // R2 swizzle
  const int g      = (bid >> 3) & 3;
  const int b      = sample >> 3;
  const int tid    = threadIdx.x;
  const int lane   = tid & 63;
  const int wid    = tid >> 6;          // 0..7
  const int l16    = lane & 15;
  const int lk     = lane >> 4;         // 0..3

  f32x4 acc[2][8];
#pragma unroll
  for (int m2 = 0; m2 < 2; ++m2)
#pragma unroll
    for (int n = 0; n < 8; ++n) acc[m2][n] = (f32x4){0.f,0.f,0.f,0.f};

  const size_t wb_base = (size_t)b * 5 * 128 * 64;
  const float* xsamp = x + (size_t)sample * 64 * 2048;

#pragma unroll
  for (int ph = 0; ph < 4; ++ph) {
    const int th = ph >> 1;             // t-half: out t in [th*512, th*512+512)
    const int ch = ph & 1;              // ci chunk: [ch*32, ch*32+32)

    if (ph) __syncthreads();            // previous compute done before overwrite
    // ---- stage: x[ci ch*32..+32][th*1024-2 .. th*1024+1025] -> xe/xo (bf16)
    {
      const float* xbase = xsamp + (size_t)(ch * 32) * 2048;
      const float* xr = xbase + (size_t)(wid * 4) * 2048 + th * 1024;
#pragma unroll 2
      for (int pass = 0; pass < 8; ++pass) {
        int c0 = pass * 128 + lane * 2;             // local x-col (8B aligned)
        float2 v0 = *(const float2*)(xr + 0 * 2048 + c0);
        float2 v1 = *(const float2*)(xr + 1 * 2048 + c0);
        float2 v2 = *(const float2*)(xr + 2 * 2048 + c0);
        float2 v3 = *(const float2*)(xr + 3 * 2048 + c0);
        int pcol = pass * 64 + lane + 1;            // lane->pcol stride 1
        int2 ev = { pk2(v0.x, v1.x), pk2(v2.x, v3.x) };
        int2 od = { pk2(v0.y, v1.y), pk2(v2.y, v3.y) };
        *(int2*)(xe + pcol * PITCH + wid * 4) = ev;
        *(int2*)(xo + pcol * PITCH + wid * 4) = od;
      }
      // halo cols: pcol 0 (x-cols th*1024-2/-1) and pcol 513 (+1024/+1025)
      if (tid < 128) {
        int which = tid >> 5;           // 0:L-even 1:L-odd 2:R-even 3:R-odd
        int ci    = tid & 31;
        int xc    = th * 1024 + ((which < 2) ? (which - 2) : (1024 + (which & 1)));
        float v = (xc >= 0 && xc < 2048) ? xbase[(size_t)ci * 2048 + xc] : 0.f;
        short* arr = (which & 1) ? xo : xe;
        arr[((which < 2) ? 0 : 513) * PITCH + ci] = f2bf(v);
      }
    }
    __syncthreads();
    // ---- compute: 5 taps x 4 n-frags x 2 m-frags, K=32 (this ci chunk)
#pragma unroll
    for (int j = 0; j < 5; ++j) {
      const short* apb = Wb + wb_base + (size_t)(j * 128 + g * 32) * 64 + ch * 32 + lk * 8;
      bf16x8 a0 = *(const bf16x8*)(apb + (size_t)l16 * 64);
      bf16x8 a1 = *(const bf16x8*)(apb + (size_t)(l16 + 16) * 64);
      const short* arr = (j & 1) ? xo : xe;
      const int joff = (j & 1) ? ((j - 1) >> 1) : (j >> 1);
#pragma unroll
      for (int nn = 0; nn < 4; ++nn) {
        int tloc = wid * 64 + nn * 16 + l16;        // t within this half
        const short* bp = arr + (tloc + joff) * PITCH + lk * 8;
        bf16x4 lo = *(const bf16x4*)bp;
        bf16x4 hi = *(const bf16x4*)(bp + 4);
        bf16x8 bfr = {lo[0],lo[1],lo[2],lo[3],hi[0],hi[1],hi[2],hi[3]};
        const int n = th * 4 + nn;                  // static (ph unrolled)
        acc[0][n] = __builtin_amdgcn_mfma_f32_16x16x32_bf16(a0, bfr, acc[0][n], 0, 0, 0);
        acc[1][n] = __builtin_amdgcn_mfma_f32_16x16x32_bf16(a1, bfr, acc[1][n], 0, 0, 0);
      }
    }
  }

  // ---- epilogue: bias + ReLU + GroupNorm over 32co x 1024t
  float cb_[2][4], ga_[2][4], be_[2][4];
#pragma unroll
  for (int m2 = 0; m2 < 2; ++m2)
#pragma unroll
    for (int r = 0; r < 4; ++r) {
      int co = g * 32 + m2 * 16 + lk * 4 + r;
      cb_[m2][r] = conv_b[co];
      ga_[m2][r] = gamma[co];
      be_[m2][r] = beta[co];
    }
  float s1 = 0.f, s2 = 0.f;
#pragma unroll
  for (int m2 = 0; m2 < 2; ++m2)
#pragma unroll
    for (int n = 0; n < 8; ++n)
#pragma unroll
      for (int r = 0; r < 4; ++r) {
        float v = acc[m2][n][r] + cb_[m2][r];
        v = v > 0.f ? v : 0.f;
        acc[m2][n][r] = v;
        s1 += v;
        s2 = fmaf(v, v, s2);
      }
#pragma unroll
  for (int off = 32; off; off >>= 1) {
    s1 += __shfl_down(s1, off);
    s2 += __shfl_down(s2, off);
  }
  if (lane == 0) { redS[wid] = s1; redQ[wid] = s2; }
  __syncthreads();
  if (tid == 0) {
    float a = 0.f, q = 0.f;
#pragma unroll
    for (int w = 0; w < 8; ++w) { a += redS[w]; q += redQ[w]; }
    float mean = a * (1.f / 32768.f);
    float var  = q * (1.f / 32768.f) - mean * mean;
    bc2[0] = mean;
    bc2[1] = rsqrtf(var + EPSV);
  }
  __syncthreads();
  const float mean = bc2[0], inv = bc2[1];
  float* ob = out + (size_t)sample * 128 * 1024;
#pragma unroll
  for (int m2 = 0; m2 < 2; ++m2)
#pragma unroll
    for (int r = 0; r < 4; ++r) {
      int co = g * 32 + m2 * 16 + lk * 4 + r;
      float aa = ga_[m2][r] * inv;
      float bb = be_[m2][r] - mean * aa;
      float* orow = ob + (size_t)co * 1024 + l16;
#pragma unroll
      for (int n = 0; n < 8; ++n) {
        int t = (n >> 2) * 512 + wid * 64 + (n & 3) * 16;
        orow[t] = acc[m2][n][r] * aa + bb;
      }
    }
}

// ---------------------------------------------------------------------------
extern "C" void kernel_launch(void* const* d_in, const int* in_sizes, int n_in,
                              void* d_out, int out_size, void* d_ws, size_t ws_size,
                              hipStream_t stream) {
  const float* x       = (const float*)d_in[0];
  const float* A_flat  = (const float*)d_in[1];
  const float* B_flat  = (const float*)d_in[2];
  const float* conv_w  = (const float*)d_in[3];
  const float* conv_b  = (const float*)d_in[4];
  const float* gamma   = (const float*)d_in[5];
  const float* beta    = (const float*)d_in[6];
  const float* scale_p = (const float*)d_in[9];

  float* out = (float*)d_out;
  short* Wb  = (short*)d_ws;   // 32*5*128*64 bf16 = 2.62 MB

  build_weights<<<5120, 256, 0, stream>>>(A_flat, B_flat, conv_w, scale_p, Wb);
  conv_gn_mfma<<<1024, 512, 0, stream>>>(x, Wb, conv_b, gamma, beta, out);
}